// Round 3
// baseline (77.980 us; speedup 1.0000x reference)
//
#include <hip/hip_runtime.h>

// Periodogram: out[b,m] = (re^2 + im^2)/N
//   re = sum_n a[b,n]*cos(2pi*xg[m]*n) + b[b,n]*sin(2pi*xg[m]*n)
//   im = sum_n b[b,n]*cos(2pi*xg[m]*n) - a[b,n]*sin(2pi*xg[m]*n)
// Implemented as f16 MFMA GEMMs with on-the-fly trig tile generation.

typedef __fp16 half8 __attribute__((ext_vector_type(8)));
typedef __fp16 half2v __attribute__((ext_vector_type(2)));
typedef float f32x4 __attribute__((ext_vector_type(4)));

#define B_SZ 512
#define N_SZ 1024
#define M_SZ 16384
#define BT 128
#define MT 128
#define KT 32

// Fragment-linear LDS layout for a [128][32] f16 tile:
// idx-block fb = idx>>4 (1024 B each); within block, lane (g= k>>3)*16 + (idx&15)
// holds 8 contiguous halves k = g*8 .. g*8+7 at lane*16 bytes.
// Both A-side and B-side tiles use the SAME convention, so any consistent
// hardware within-k permutation cancels (permutation argument).
__device__ __forceinline__ unsigned ldsOff(int idx, int k) {
    return (unsigned)(((idx >> 4) << 10) + ((((k >> 3) << 4) + (idx & 15)) << 4) + ((k & 7) << 1));
}

union U2 { half2v h2[2]; uint2 u; };

__global__ __launch_bounds__(256, 2)
void periodogram_kernel(const float* __restrict__ x, const float* __restrict__ xgrid,
                        float* __restrict__ out) {
    // LDS tiles: A(a) | B(b) | C(cos) | S(sin) | NS(-sin), 8 KB each
    __shared__ __align__(16) unsigned char smem[5 * 8192];
    const int tid  = (int)threadIdx.x;
    const int lane = tid & 63;
    const int w    = tid >> 6;
    const int btile = (int)blockIdx.x & 3;
    const int mtile = (int)blockIdx.x >> 2;
    const int b0 = btile * BT;
    const int m0 = mtile * MT;

    // staging assignment: thread -> (row = row8 + rep*32, k-chunk kk)
    const int row8 = tid >> 3;          // 0..31
    const int kk   = (tid & 7) * 4;     // 0,4,...,28
    float xg[4];
#pragma unroll
    for (int rep = 0; rep < 4; ++rep) xg[rep] = xgrid[m0 + row8 + rep * 32];

    f32x4 accRe[4][4], accIm[4][4];
#pragma unroll
    for (int i = 0; i < 4; ++i)
#pragma unroll
        for (int j = 0; j < 4; ++j) { accRe[i][j] = (f32x4)0.0f; accIm[i][j] = (f32x4)0.0f; }

    const int wr = (w >> 1) * 64;   // wave's row offset inside 128
    const int wc = (w & 1) * 64;    // wave's col offset inside 128
    const unsigned aBase  = 0u     + (unsigned)((wr >> 4) << 10) + (unsigned)(lane << 4);
    const unsigned bBase  = 8192u  + (unsigned)((wr >> 4) << 10) + (unsigned)(lane << 4);
    const unsigned cBase  = 16384u + (unsigned)((wc >> 4) << 10) + (unsigned)(lane << 4);
    const unsigned sBase  = 24576u + (unsigned)((wc >> 4) << 10) + (unsigned)(lane << 4);
    const unsigned nsBase = 32768u + (unsigned)((wc >> 4) << 10) + (unsigned)(lane << 4);

    for (int t = 0; t < N_SZ / KT; ++t) {
        const int k0 = t * KT;
        __syncthreads();   // previous iteration's reads are done
        // ---------------- stage tile t ----------------
#pragma unroll
        for (int rep = 0; rep < 4; ++rep) {
            const int row = row8 + rep * 32;
            const unsigned off = ldsOff(row, kk);
            // x: a = x[b,0,:], b = x[b,1,:]
            const float4 va = *(const float4*)(x + ((size_t)(b0 + row) * 2 + 0) * N_SZ + k0 + kk);
            const float4 vb = *(const float4*)(x + ((size_t)(b0 + row) * 2 + 1) * N_SZ + k0 + kk);
            U2 pa, pb;
            pa.h2[0] = __builtin_amdgcn_cvt_pkrtz(va.x, va.y);
            pa.h2[1] = __builtin_amdgcn_cvt_pkrtz(va.z, va.w);
            pb.h2[0] = __builtin_amdgcn_cvt_pkrtz(vb.x, vb.y);
            pb.h2[1] = __builtin_amdgcn_cvt_pkrtz(vb.z, vb.w);
            *(uint2*)(smem + 0    + off) = pa.u;
            *(uint2*)(smem + 8192 + off) = pb.u;
            // trig: row here is the m-local index
            float c[4], s[4];
            const float xgv = xg[rep];
#pragma unroll
            for (int j = 0; j < 4; ++j) {
                const float kf = (float)(k0 + kk + j);
                const float p  = xgv * kf;
                const float e  = __builtin_fmaf(xgv, kf, -p);   // exact residual of the product
                const float f  = (p - floorf(p)) + e;           // phase in revolutions, ~[0,1)
                c[j] = __builtin_amdgcn_cosf(f);                // v_cos: cos(2*pi*f)
                s[j] = __builtin_amdgcn_sinf(f);                // v_sin: sin(2*pi*f)
            }
            U2 pc, ps, pn;
            pc.h2[0] = __builtin_amdgcn_cvt_pkrtz(c[0], c[1]);
            pc.h2[1] = __builtin_amdgcn_cvt_pkrtz(c[2], c[3]);
            ps.h2[0] = __builtin_amdgcn_cvt_pkrtz(s[0], s[1]);
            ps.h2[1] = __builtin_amdgcn_cvt_pkrtz(s[2], s[3]);
            pn.h2[0] = __builtin_amdgcn_cvt_pkrtz(-s[0], -s[1]);
            pn.h2[1] = __builtin_amdgcn_cvt_pkrtz(-s[2], -s[3]);
            *(uint2*)(smem + 16384 + off) = pc.u;
            *(uint2*)(smem + 24576 + off) = ps.u;
            *(uint2*)(smem + 32768 + off) = pn.u;
        }
        __syncthreads();
        // ---------------- compute tile t ----------------
        half8 fa[4], fb[4];
#pragma unroll
        for (int fm = 0; fm < 4; ++fm) {
            fa[fm] = *(const half8*)(smem + aBase + fm * 1024);
            fb[fm] = *(const half8*)(smem + bBase + fm * 1024);
        }
#pragma unroll
        for (int fn = 0; fn < 4; ++fn) {
            const half8 fc  = *(const half8*)(smem + cBase  + fn * 1024);
            const half8 fs  = *(const half8*)(smem + sBase  + fn * 1024);
            const half8 fns = *(const half8*)(smem + nsBase + fn * 1024);
#pragma unroll
            for (int fm = 0; fm < 4; ++fm) {
                accRe[fm][fn] = __builtin_amdgcn_mfma_f32_16x16x32_f16(fa[fm], fc,  accRe[fm][fn], 0, 0, 0);
                accRe[fm][fn] = __builtin_amdgcn_mfma_f32_16x16x32_f16(fb[fm], fs,  accRe[fm][fn], 0, 0, 0);
                accIm[fm][fn] = __builtin_amdgcn_mfma_f32_16x16x32_f16(fb[fm], fc,  accIm[fm][fn], 0, 0, 0);
                accIm[fm][fn] = __builtin_amdgcn_mfma_f32_16x16x32_f16(fa[fm], fns, accIm[fm][fn], 0, 0, 0);
            }
        }
    }

    // ---------------- epilogue: out = (re^2 + im^2)/N ----------------
    // D frag layout (measured m89): col = lane&15, row = (lane>>4)*4 + reg
    const float inv = 1.0f / (float)N_SZ;
    const int orow0 = b0 + wr + ((lane >> 4) << 2);
    const int ocol0 = m0 + wc + (lane & 15);
#pragma unroll
    for (int fm = 0; fm < 4; ++fm)
#pragma unroll
        for (int fn = 0; fn < 4; ++fn) {
            const f32x4 r = accRe[fm][fn];
            const f32x4 im = accIm[fm][fn];
            const int col = ocol0 + fn * 16;
#pragma unroll
            for (int j = 0; j < 4; ++j) {
                const int row = orow0 + fm * 16 + j;
                out[(size_t)row * M_SZ + col] = (r[j] * r[j] + im[j] * im[j]) * inv;
            }
        }
}

extern "C" void kernel_launch(void* const* d_in, const int* in_sizes, int n_in,
                              void* d_out, int out_size, void* d_ws, size_t ws_size,
                              hipStream_t stream) {
    const float* x     = (const float*)d_in[0];
    const float* xgrid = (const float*)d_in[1];
    float* out = (float*)d_out;
    dim3 grid(B_SZ / BT * (M_SZ / MT));   // 4 * 128 = 512 blocks
    dim3 block(256);
    periodogram_kernel<<<grid, block, 0, stream>>>(x, xgrid, out);
}